// Round 2
// baseline (671.926 us; speedup 1.0000x reference)
//
#include <hip/hip_runtime.h>
#include <float.h>
#include <math.h>

// Problem constants (from reference)
#define N_DB   200000
#define D_EMB  512
#define K      32

// Kernel-1 config: 512 blocks x 512 threads = 2 blocks/CU, 16 waves/CU
#define NBLK   512
#define TPB    512
#define WAVES  (TPB / 64)                    // 8 waves/block
#define RPB    ((N_DB + NBLK - 1) / NBLK)    // 391 rows per block
#define NCAND  (NBLK * K)                    // 16384 candidates

// Kernel-2 config
#define TPB2   512
#define WAVES2 (TPB2 / 64)

// ---------------------------------------------------------------------------
// Kernel 1: per-block distance computation + local top-32 selection.
// Each wave owns a CONTIGUOUS sub-range of the block's rows and processes
// 4 rows per iteration: 8 independent float4 loads in flight (8 KB/wave)
// and 4 independent shuffle-reduce chains that pipeline in the DS unit.
// ---------------------------------------------------------------------------
__global__ __launch_bounds__(TPB) void knn_dist_topk(
    const float* __restrict__ x,
    const float* __restrict__ X_emb,
    float* __restrict__ cand_d,
    int*   __restrict__ cand_i)
{
    __shared__ float xs[D_EMB];
    __shared__ float dists[RPB];
    __shared__ float redv[WAVES];
    __shared__ int   redi[WAVES];

    const int tid  = threadIdx.x;
    const int wid  = tid >> 6;
    const int lane = tid & 63;
    const int base = blockIdx.x * RPB;
    const int rows = min(RPB, N_DB - base);

    // Stage query vector in LDS
    for (int i = tid; i < D_EMB; i += TPB) xs[i] = x[i];
    __syncthreads();

    const float4* xq = (const float4*)xs;
    const float4 q0 = xq[lane];
    const float4 q1 = xq[lane + 64];

    // Contiguous per-wave row range
    const int per_wave = (rows + WAVES - 1) / WAVES;
    const int w0 = min(wid * per_wave, rows);
    const int w1 = min(w0 + per_wave, rows);

    int r = w0;
    // Bulk: 4 rows per iteration
    for (; r + 4 <= w1; r += 4) {
        const float* rp = X_emb + (size_t)(base + r) * D_EMB;
        const float4* p0 = (const float4*)(rp);
        const float4* p1 = (const float4*)(rp + D_EMB);
        const float4* p2 = (const float4*)(rp + 2 * D_EMB);
        const float4* p3 = (const float4*)(rp + 3 * D_EMB);
        float4 a0 = p0[lane], b0 = p0[lane + 64];
        float4 a1 = p1[lane], b1 = p1[lane + 64];
        float4 a2 = p2[lane], b2 = p2[lane + 64];
        float4 a3 = p3[lane], b3 = p3[lane + 64];
        float s0 = 0.f, s1 = 0.f, s2 = 0.f, s3 = 0.f, d;
        d = a0.x - q0.x; s0 = fmaf(d, d, s0);
        d = a0.y - q0.y; s0 = fmaf(d, d, s0);
        d = a0.z - q0.z; s0 = fmaf(d, d, s0);
        d = a0.w - q0.w; s0 = fmaf(d, d, s0);
        d = b0.x - q1.x; s0 = fmaf(d, d, s0);
        d = b0.y - q1.y; s0 = fmaf(d, d, s0);
        d = b0.z - q1.z; s0 = fmaf(d, d, s0);
        d = b0.w - q1.w; s0 = fmaf(d, d, s0);
        d = a1.x - q0.x; s1 = fmaf(d, d, s1);
        d = a1.y - q0.y; s1 = fmaf(d, d, s1);
        d = a1.z - q0.z; s1 = fmaf(d, d, s1);
        d = a1.w - q0.w; s1 = fmaf(d, d, s1);
        d = b1.x - q1.x; s1 = fmaf(d, d, s1);
        d = b1.y - q1.y; s1 = fmaf(d, d, s1);
        d = b1.z - q1.z; s1 = fmaf(d, d, s1);
        d = b1.w - q1.w; s1 = fmaf(d, d, s1);
        d = a2.x - q0.x; s2 = fmaf(d, d, s2);
        d = a2.y - q0.y; s2 = fmaf(d, d, s2);
        d = a2.z - q0.z; s2 = fmaf(d, d, s2);
        d = a2.w - q0.w; s2 = fmaf(d, d, s2);
        d = b2.x - q1.x; s2 = fmaf(d, d, s2);
        d = b2.y - q1.y; s2 = fmaf(d, d, s2);
        d = b2.z - q1.z; s2 = fmaf(d, d, s2);
        d = b2.w - q1.w; s2 = fmaf(d, d, s2);
        d = a3.x - q0.x; s3 = fmaf(d, d, s3);
        d = a3.y - q0.y; s3 = fmaf(d, d, s3);
        d = a3.z - q0.z; s3 = fmaf(d, d, s3);
        d = a3.w - q0.w; s3 = fmaf(d, d, s3);
        d = b3.x - q1.x; s3 = fmaf(d, d, s3);
        d = b3.y - q1.y; s3 = fmaf(d, d, s3);
        d = b3.z - q1.z; s3 = fmaf(d, d, s3);
        d = b3.w - q1.w; s3 = fmaf(d, d, s3);
        // 4 independent reduce chains -> pipelined in DS unit
        #pragma unroll
        for (int off = 32; off > 0; off >>= 1) {
            s0 += __shfl_xor(s0, off);
            s1 += __shfl_xor(s1, off);
            s2 += __shfl_xor(s2, off);
            s3 += __shfl_xor(s3, off);
        }
        if (lane == 0) {
            dists[r]     = sqrtf(s0);
            dists[r + 1] = sqrtf(s1);
            dists[r + 2] = sqrtf(s2);
            dists[r + 3] = sqrtf(s3);
        }
    }
    // Tail: single rows
    for (; r < w1; ++r) {
        const float4* p = (const float4*)(X_emb + (size_t)(base + r) * D_EMB);
        float4 a = p[lane];
        float4 b = p[lane + 64];
        float s = 0.f, d;
        d = a.x - q0.x; s = fmaf(d, d, s);
        d = a.y - q0.y; s = fmaf(d, d, s);
        d = a.z - q0.z; s = fmaf(d, d, s);
        d = a.w - q0.w; s = fmaf(d, d, s);
        d = b.x - q1.x; s = fmaf(d, d, s);
        d = b.y - q1.y; s = fmaf(d, d, s);
        d = b.z - q1.z; s = fmaf(d, d, s);
        d = b.w - q1.w; s = fmaf(d, d, s);
        #pragma unroll
        for (int off = 32; off > 0; off >>= 1) s += __shfl_xor(s, off);
        if (lane == 0) dists[r] = sqrtf(s);
    }
    __syncthreads();

    // Selection phase: 32 masked arg-min passes over LDS dists
    for (int it = 0; it < K; ++it) {
        float bv = FLT_MAX;
        int   bi = 0x7FFFFFFF;
        for (int i = tid; i < rows; i += TPB) {
            float v = dists[i];
            if (v < bv) { bv = v; bi = i; }   // strict < keeps lowest index
        }
        #pragma unroll
        for (int off = 32; off > 0; off >>= 1) {
            float ov = __shfl_xor(bv, off);
            int   oi = __shfl_xor(bi, off);
            if (ov < bv || (ov == bv && oi < bi)) { bv = ov; bi = oi; }
        }
        if (lane == 0) { redv[wid] = bv; redi[wid] = bi; }
        __syncthreads();
        if (tid == 0) {
            float v = redv[0]; int b = redi[0];
            #pragma unroll
            for (int w = 1; w < WAVES; ++w) {
                if (redv[w] < v || (redv[w] == v && redi[w] < b)) {
                    v = redv[w]; b = redi[w];
                }
            }
            cand_d[blockIdx.x * K + it] = v;
            cand_i[blockIdx.x * K + it] = base + b;
            if (b >= 0 && b < rows) dists[b] = FLT_MAX;  // mask selected
        }
        __syncthreads();
    }
}

// ---------------------------------------------------------------------------
// Kernel 2: reduce 16384 candidates -> global top-32 (ascending), gather
// neighbor rows / classes / distances into d_out.
// Candidate slot order equals db-index order for equal distances, so
// slot-order tie-break reproduces jax.lax.top_k's lowest-index semantics.
// ---------------------------------------------------------------------------
__global__ __launch_bounds__(TPB2) void knn_final(
    const float* __restrict__ X_emb,
    const int*   __restrict__ X_cls,
    const float* __restrict__ cand_d,
    const int*   __restrict__ cand_i,
    float* __restrict__ out)
{
    __shared__ float cd[NCAND];      // 64 KiB
    __shared__ float redv[WAVES2];
    __shared__ int   redi[WAVES2];
    __shared__ int   sel_i[K];
    __shared__ float sel_d[K];

    const int tid  = threadIdx.x;
    const int wid  = tid >> 6;
    const int lane = tid & 63;

    for (int i = tid; i < NCAND; i += TPB2) cd[i] = cand_d[i];
    __syncthreads();

    for (int it = 0; it < K; ++it) {
        float bv = FLT_MAX;
        int   bi = 0x7FFFFFFF;
        for (int i = tid; i < NCAND; i += TPB2) {
            float v = cd[i];
            if (v < bv) { bv = v; bi = i; }
        }
        #pragma unroll
        for (int off = 32; off > 0; off >>= 1) {
            float ov = __shfl_xor(bv, off);
            int   oi = __shfl_xor(bi, off);
            if (ov < bv || (ov == bv && oi < bi)) { bv = ov; bi = oi; }
        }
        if (lane == 0) { redv[wid] = bv; redi[wid] = bi; }
        __syncthreads();
        if (tid == 0) {
            float v = redv[0]; int b = redi[0];
            #pragma unroll
            for (int w = 1; w < WAVES2; ++w) {
                if (redv[w] < v || (redv[w] == v && redi[w] < b)) {
                    v = redv[w]; b = redi[w];
                }
            }
            sel_d[it] = v;
            sel_i[it] = cand_i[b];   // one L2 read by thread 0
            cd[b] = FLT_MAX;
        }
        __syncthreads();
    }

    // Gather: out layout = emb[32*512] | cls[32] | dist[32]
    float4* out_emb = (float4*)out;
    for (int rr = wid; rr < K; rr += WAVES2) {
        const float4* p = (const float4*)(X_emb + (size_t)sel_i[rr] * D_EMB);
        out_emb[rr * 128 + lane]      = p[lane];
        out_emb[rr * 128 + lane + 64] = p[lane + 64];
    }
    if (tid < K) {
        out[K * D_EMB + tid]     = (float)X_cls[sel_i[tid]];
        out[K * D_EMB + K + tid] = sel_d[tid];
    }
}

extern "C" void kernel_launch(void* const* d_in, const int* in_sizes, int n_in,
                              void* d_out, int out_size, void* d_ws, size_t ws_size,
                              hipStream_t stream) {
    const float* x     = (const float*)d_in[0];
    const float* X_emb = (const float*)d_in[1];
    const int*   X_cls = (const int*)d_in[2];
    // d_in[3] is k == 32 (hard-coded)

    float* cand_d = (float*)d_ws;
    int*   cand_i = (int*)((char*)d_ws + NCAND * sizeof(float));

    knn_dist_topk<<<NBLK, TPB, 0, stream>>>(x, X_emb, cand_d, cand_i);
    knn_final<<<1, TPB2, 0, stream>>>(X_emb, X_cls, cand_d, cand_i, (float*)d_out);
}

// Round 3
// 622.987 us; speedup vs baseline: 1.0786x; 1.0786x over previous
//
#include <hip/hip_runtime.h>
#include <float.h>
#include <math.h>

// Problem constants (from reference)
#define N_DB   200000
#define D_EMB  512
#define K      32

// Kernel-1 config: 512 blocks x 512 threads
#define NBLK   512
#define TPB    512
#define WAVES  (TPB / 64)                    // 8 waves/block
#define RPB    ((N_DB + NBLK - 1) / NBLK)    // 391 rows per block
#define SELREG ((RPB + 63) / 64)             // 7 regs/lane for selection
#define NCAND  (NBLK * K)                    // 16384 candidates

// Kernel-2 config
#define TPB2   512
#define WAVES2 (TPB2 / 64)                   // 8
#define CPW    (NCAND / WAVES2)              // 2048 candidates per wave
#define CREG   (CPW / 64)                    // 32 regs per lane

typedef float v4f __attribute__((ext_vector_type(4)));

// ---------------------------------------------------------------------------
// Kernel 1: streaming squared-distance computation + wave-0 register top-32.
// Distance phase: 4 rows/iteration, 8 independent nontemporal float4 loads.
// Selection phase: wave 0 only — dists cached in 7 regs/lane, 32 barrier-free
// shfl-argmin passes (tie-break: lowest db index).
// ---------------------------------------------------------------------------
__global__ __launch_bounds__(TPB) void knn_dist_topk(
    const float* __restrict__ x,
    const float* __restrict__ X_emb,
    float* __restrict__ cand_d,
    int*   __restrict__ cand_i)
{
    __shared__ float xs[D_EMB];
    __shared__ float dists[RPB];

    const int tid  = threadIdx.x;
    const int wid  = tid >> 6;
    const int lane = tid & 63;
    const int base = blockIdx.x * RPB;
    const int rows = min(RPB, N_DB - base);

    // Stage query vector in LDS
    for (int i = tid; i < D_EMB; i += TPB) xs[i] = x[i];
    __syncthreads();

    const v4f* xq = (const v4f*)xs;
    const v4f q0 = xq[lane];
    const v4f q1 = xq[lane + 64];

    // Contiguous per-wave row range
    const int per_wave = (rows + WAVES - 1) / WAVES;
    const int w0 = min(wid * per_wave, rows);
    const int w1 = min(w0 + per_wave, rows);

    int r = w0;
    for (; r + 4 <= w1; r += 4) {
        const float* rp = X_emb + (size_t)(base + r) * D_EMB;
        const v4f* p0 = (const v4f*)(rp);
        const v4f* p1 = (const v4f*)(rp + D_EMB);
        const v4f* p2 = (const v4f*)(rp + 2 * D_EMB);
        const v4f* p3 = (const v4f*)(rp + 3 * D_EMB);
        v4f a0 = __builtin_nontemporal_load(&p0[lane]);
        v4f b0 = __builtin_nontemporal_load(&p0[lane + 64]);
        v4f a1 = __builtin_nontemporal_load(&p1[lane]);
        v4f b1 = __builtin_nontemporal_load(&p1[lane + 64]);
        v4f a2 = __builtin_nontemporal_load(&p2[lane]);
        v4f b2 = __builtin_nontemporal_load(&p2[lane + 64]);
        v4f a3 = __builtin_nontemporal_load(&p3[lane]);
        v4f b3 = __builtin_nontemporal_load(&p3[lane + 64]);
        float s0 = 0.f, s1 = 0.f, s2 = 0.f, s3 = 0.f, d;
        d = a0.x - q0.x; s0 = fmaf(d, d, s0);
        d = a0.y - q0.y; s0 = fmaf(d, d, s0);
        d = a0.z - q0.z; s0 = fmaf(d, d, s0);
        d = a0.w - q0.w; s0 = fmaf(d, d, s0);
        d = b0.x - q1.x; s0 = fmaf(d, d, s0);
        d = b0.y - q1.y; s0 = fmaf(d, d, s0);
        d = b0.z - q1.z; s0 = fmaf(d, d, s0);
        d = b0.w - q1.w; s0 = fmaf(d, d, s0);
        d = a1.x - q0.x; s1 = fmaf(d, d, s1);
        d = a1.y - q0.y; s1 = fmaf(d, d, s1);
        d = a1.z - q0.z; s1 = fmaf(d, d, s1);
        d = a1.w - q0.w; s1 = fmaf(d, d, s1);
        d = b1.x - q1.x; s1 = fmaf(d, d, s1);
        d = b1.y - q1.y; s1 = fmaf(d, d, s1);
        d = b1.z - q1.z; s1 = fmaf(d, d, s1);
        d = b1.w - q1.w; s1 = fmaf(d, d, s1);
        d = a2.x - q0.x; s2 = fmaf(d, d, s2);
        d = a2.y - q0.y; s2 = fmaf(d, d, s2);
        d = a2.z - q0.z; s2 = fmaf(d, d, s2);
        d = a2.w - q0.w; s2 = fmaf(d, d, s2);
        d = b2.x - q1.x; s2 = fmaf(d, d, s2);
        d = b2.y - q1.y; s2 = fmaf(d, d, s2);
        d = b2.z - q1.z; s2 = fmaf(d, d, s2);
        d = b2.w - q1.w; s2 = fmaf(d, d, s2);
        d = a3.x - q0.x; s3 = fmaf(d, d, s3);
        d = a3.y - q0.y; s3 = fmaf(d, d, s3);
        d = a3.z - q0.z; s3 = fmaf(d, d, s3);
        d = a3.w - q0.w; s3 = fmaf(d, d, s3);
        d = b3.x - q1.x; s3 = fmaf(d, d, s3);
        d = b3.y - q1.y; s3 = fmaf(d, d, s3);
        d = b3.z - q1.z; s3 = fmaf(d, d, s3);
        d = b3.w - q1.w; s3 = fmaf(d, d, s3);
        #pragma unroll
        for (int off = 32; off > 0; off >>= 1) {
            s0 += __shfl_xor(s0, off);
            s1 += __shfl_xor(s1, off);
            s2 += __shfl_xor(s2, off);
            s3 += __shfl_xor(s3, off);
        }
        if (lane == 0) {
            dists[r]     = s0;   // squared distance; sqrt deferred to kernel 2
            dists[r + 1] = s1;
            dists[r + 2] = s2;
            dists[r + 3] = s3;
        }
    }
    for (; r < w1; ++r) {
        const v4f* p = (const v4f*)(X_emb + (size_t)(base + r) * D_EMB);
        v4f a = __builtin_nontemporal_load(&p[lane]);
        v4f b = __builtin_nontemporal_load(&p[lane + 64]);
        float s = 0.f, d;
        d = a.x - q0.x; s = fmaf(d, d, s);
        d = a.y - q0.y; s = fmaf(d, d, s);
        d = a.z - q0.z; s = fmaf(d, d, s);
        d = a.w - q0.w; s = fmaf(d, d, s);
        d = b.x - q1.x; s = fmaf(d, d, s);
        d = b.y - q1.y; s = fmaf(d, d, s);
        d = b.z - q1.z; s = fmaf(d, d, s);
        d = b.w - q1.w; s = fmaf(d, d, s);
        #pragma unroll
        for (int off = 32; off > 0; off >>= 1) s += __shfl_xor(s, off);
        if (lane == 0) dists[r] = s;
    }
    __syncthreads();

    // Wave-0-only register-resident top-32 (barrier-free)
    if (wid == 0) {
        float dv[SELREG];
        int   di[SELREG];
        #pragma unroll
        for (int j = 0; j < SELREG; ++j) {
            const int idx = j * 64 + lane;
            dv[j] = (idx < rows) ? dists[idx] : FLT_MAX;
            di[j] = base + idx;
        }
        for (int it = 0; it < K; ++it) {
            float bv = dv[0];
            int   bi = di[0];
            #pragma unroll
            for (int j = 1; j < SELREG; ++j) {
                if (dv[j] < bv || (dv[j] == bv && di[j] < bi)) { bv = dv[j]; bi = di[j]; }
            }
            #pragma unroll
            for (int off = 32; off > 0; off >>= 1) {
                float ov = __shfl_xor(bv, off);
                int   oi = __shfl_xor(bi, off);
                if (ov < bv || (ov == bv && oi < bi)) { bv = ov; bi = oi; }
            }
            if (lane == 0) {
                cand_d[blockIdx.x * K + it] = bv;
                cand_i[blockIdx.x * K + it] = bi;
            }
            #pragma unroll
            for (int j = 0; j < SELREG; ++j) if (di[j] == bi) dv[j] = FLT_MAX;
        }
    }
}

// ---------------------------------------------------------------------------
// Kernel 2: two-stage register-resident reduction of 16384 candidates,
// then gather rows/classes/distances. Tie-break everywhere: lowest db index.
// ---------------------------------------------------------------------------
__global__ __launch_bounds__(TPB2) void knn_final(
    const float* __restrict__ X_emb,
    const int*   __restrict__ X_cls,
    const float* __restrict__ cand_d,
    const int*   __restrict__ cand_i,
    float* __restrict__ out)
{
    __shared__ float sd[WAVES2 * K];
    __shared__ int   si[WAVES2 * K];
    __shared__ float fd[K];
    __shared__ int   fi[K];

    const int tid  = threadIdx.x;
    const int wid  = tid >> 6;
    const int lane = tid & 63;

    // Stage A: each wave owns 2048 candidates in registers, emits its top-32
    {
        float dv[CREG];
        int   di[CREG];
        const int cbase = wid * CPW;
        #pragma unroll
        for (int j = 0; j < CREG; ++j) {
            const int c = cbase + j * 64 + lane;
            dv[j] = cand_d[c];
            di[j] = cand_i[c];
        }
        for (int it = 0; it < K; ++it) {
            float bv = dv[0];
            int   bi = di[0];
            #pragma unroll
            for (int j = 1; j < CREG; ++j) {
                if (dv[j] < bv || (dv[j] == bv && di[j] < bi)) { bv = dv[j]; bi = di[j]; }
            }
            #pragma unroll
            for (int off = 32; off > 0; off >>= 1) {
                float ov = __shfl_xor(bv, off);
                int   oi = __shfl_xor(bi, off);
                if (ov < bv || (ov == bv && oi < bi)) { bv = ov; bi = oi; }
            }
            if (lane == 0) { sd[wid * K + it] = bv; si[wid * K + it] = bi; }
            #pragma unroll
            for (int j = 0; j < CREG; ++j) if (di[j] == bi) dv[j] = FLT_MAX;
        }
    }
    __syncthreads();

    // Stage B: wave 0 reduces 256 survivors to the final 32 (ascending)
    if (wid == 0) {
        float ev[4];
        int   ei[4];
        #pragma unroll
        for (int j = 0; j < 4; ++j) {
            const int idx = j * 64 + lane;
            ev[j] = sd[idx];
            ei[j] = si[idx];
        }
        for (int it = 0; it < K; ++it) {
            float bv = ev[0];
            int   bi = ei[0];
            #pragma unroll
            for (int j = 1; j < 4; ++j) {
                if (ev[j] < bv || (ev[j] == bv && ei[j] < bi)) { bv = ev[j]; bi = ei[j]; }
            }
            #pragma unroll
            for (int off = 32; off > 0; off >>= 1) {
                float ov = __shfl_xor(bv, off);
                int   oi = __shfl_xor(bi, off);
                if (ov < bv || (ov == bv && oi < bi)) { bv = ov; bi = oi; }
            }
            if (lane == 0) { fd[it] = sqrtf(bv); fi[it] = bi; }
            #pragma unroll
            for (int j = 0; j < 4; ++j) if (ei[j] == bi) ev[j] = FLT_MAX;
        }
    }
    __syncthreads();

    // Gather: out layout = emb[32*512] | cls[32] | dist[32]
    v4f* out_emb = (v4f*)out;
    for (int rr = wid; rr < K; rr += WAVES2) {
        const v4f* p = (const v4f*)(X_emb + (size_t)fi[rr] * D_EMB);
        out_emb[rr * 128 + lane]      = p[lane];
        out_emb[rr * 128 + lane + 64] = p[lane + 64];
    }
    if (tid < K) {
        out[K * D_EMB + tid]     = (float)X_cls[fi[tid]];
        out[K * D_EMB + K + tid] = fd[tid];
    }
}

extern "C" void kernel_launch(void* const* d_in, const int* in_sizes, int n_in,
                              void* d_out, int out_size, void* d_ws, size_t ws_size,
                              hipStream_t stream) {
    const float* x     = (const float*)d_in[0];
    const float* X_emb = (const float*)d_in[1];
    const int*   X_cls = (const int*)d_in[2];
    // d_in[3] is k == 32 (hard-coded)

    float* cand_d = (float*)d_ws;
    int*   cand_i = (int*)((char*)d_ws + NCAND * sizeof(float));

    knn_dist_topk<<<NBLK, TPB, 0, stream>>>(x, X_emb, cand_d, cand_i);
    knn_final<<<1, TPB2, 0, stream>>>(X_emb, X_cls, cand_d, cand_i, (float*)d_out);
}